// Round 1
// baseline (146.199 us; speedup 1.0000x reference)
//
#include <hip/hip_runtime.h>
#include <hip/hip_bf16.h>
#include <math.h>

#define DN     0.35355339059327373f   /* sqrt(1/8) */
#define RATIO  0.08838834764831845f   /* 1/sqrt(128) */
#define TEMP   0.125f

// ---------------- feature kernel (q and k share code) ----------------
template<bool IS_Q>
__global__ __launch_bounds__(256) void feat_kernel(const float* __restrict__ data,
    const float* __restrict__ proj, float* __restrict__ prime_or_dash,
    float* __restrict__ ls_out, float* __restrict__ diag_out, float* __restrict__ rmax_out)
{
    __shared__ float pT[64 * 64];     // proj transposed: pT[e][r]
    __shared__ float rowbuf[4][64];
    int tid = threadIdx.x;
#pragma unroll
    for (int i = 0; i < 16; ++i) {
        int f = tid * 16 + i;
        int r = f >> 6, e = f & 63;
        pT[e * 64 + r] = proj[f];
    }
    int wave = tid >> 6, lane = tid & 63;
    int gid = blockIdx.x * 4 + wave;            // gid = t*8 + h
    const float* row = data + ((size_t)gid << 6);
    float x = row[lane];
    rowbuf[wave][lane] = x;
    __syncthreads();

    float qq = x * x;
#pragma unroll
    for (int m = 1; m < 64; m <<= 1) qq += __shfl_xor(qq, m, 64);
    float diag = 0.0625f * qq;                  // 0.5*dn^2*|x|^2

    float dash = 0.f;
#pragma unroll
    for (int e = 0; e < 64; ++e) dash += rowbuf[wave][e] * pT[e * 64 + lane];
    dash *= DN;

    float ad = fabsf(dash);
#pragma unroll
    for (int m = 1; m < 64; m <<= 1) ad = fmaxf(ad, __shfl_xor(ad, m, 64));

    if (IS_Q) {
        prime_or_dash[((size_t)gid << 7) + lane]      = RATIO * expf(dash - ad);
        prime_or_dash[((size_t)gid << 7) + 64 + lane] = RATIO * expf(-dash - ad);
        if (lane == 0) ls_out[gid] = ad - diag;
    } else {
        prime_or_dash[((size_t)gid << 6) + lane] = dash;
        if (lane == 0) { diag_out[gid] = diag; rmax_out[gid] = ad - diag; }
    }
}

// ---------------- per-head max over s ----------------
__global__ __launch_bounds__(256) void kls_kernel(const float* __restrict__ rmax,
                                                  float* __restrict__ kls)
{
    int h = blockIdx.x, tid = threadIdx.x;
    float m = -INFINITY;
    for (int s = tid; s < 1024; s += 256) m = fmaxf(m, rmax[s * 8 + h]);
#pragma unroll
    for (int k = 1; k < 64; k <<= 1) m = fmaxf(m, __shfl_xor(m, k, 64));
    __shared__ float wm[4];
    if ((tid & 63) == 0) wm[tid >> 6] = m;
    __syncthreads();
    if (tid == 0) kls[h] = fmaxf(fmaxf(wm[0], wm[1]), fmaxf(wm[2], wm[3]));
}

// ---------------- k_prime + partial ksum / kv ----------------
__global__ __launch_bounds__(256) void kprime_kv_kernel(const float* __restrict__ kdash,
    const float* __restrict__ kdiag, const float* __restrict__ kls,
    const float* __restrict__ vin, float* __restrict__ kprime,
    float* __restrict__ pksum, float* __restrict__ pkv)
{
    __shared__ float kp_lds[64][128];
    __shared__ float v_lds[64][64];
    int tid = threadIdx.x;
    int chunk = blockIdx.x & 15, h = blockIdx.x >> 4;
    int s0 = chunk * 64;
    float ls = kls[h];
    int m = tid & 127, sg = tid >> 7;
    int r = m & 63;
    float sgn = (m < 64) ? 1.f : -1.f;
    for (int sl = sg; sl < 64; sl += 2) {
        int gid = (s0 + sl) * 8 + h;
        float dash = kdash[((size_t)gid << 6) + r];
        float val = RATIO * expf(sgn * dash - kdiag[gid] - ls);
        kp_lds[sl][m] = val;
        kprime[((size_t)gid << 7) + m] = val;
    }
#pragma unroll
    for (int i = 0; i < 16; ++i) {
        int f = tid * 16 + i;
        int sl = f >> 6, e = f & 63;
        v_lds[sl][e] = vin[((size_t)((s0 + sl) * 8 + h) << 6) + e];
    }
    __syncthreads();
    if (tid < 128) {
        float s = 0.f;
        for (int sl = 0; sl < 64; ++sl) s += kp_lds[sl][tid];
        pksum[(h * 16 + chunk) * 128 + tid] = s;
    }
    int d0 = sg * 32;
    float acc[32];
#pragma unroll
    for (int i = 0; i < 32; ++i) acc[i] = 0.f;
    for (int sl = 0; sl < 64; ++sl) {
        float kpv = kp_lds[sl][m];
#pragma unroll
        for (int i = 0; i < 32; ++i) acc[i] += kpv * v_lds[sl][d0 + i];
    }
    float* dst = pkv + ((size_t)((h * 16 + chunk) * 128 + m) << 6) + d0;
#pragma unroll
    for (int i = 0; i < 32; ++i) dst[i] = acc[i];
}

// ---------------- reduce partial kv / ksum ----------------
__global__ __launch_bounds__(256) void kvred_kernel(const float* __restrict__ pkv,
    const float* __restrict__ pksum, float* __restrict__ kv, float* __restrict__ ksum)
{
    int idx = blockIdx.x * 256 + threadIdx.x;
    if (idx < 65536) {
        int h = idx >> 13, md = idx & 8191;
        float s = 0.f;
#pragma unroll
        for (int c = 0; c < 16; ++c) s += pkv[((size_t)(h * 16 + c) << 13) + md];
        kv[idx] = s;
    } else if (idx < 66560) {
        int j = idx - 65536;
        int h = j >> 7, mm = j & 127;
        float s = 0.f;
#pragma unroll
        for (int c = 0; c < 16; ++c) s += pksum[(h * 16 + c) * 128 + mm];
        ksum[j] = s;
    }
}

// ---------------- main: local window + long-range combine ----------------
__global__ __launch_bounds__(256) void main_kernel(const float* __restrict__ q,
    const float* __restrict__ k, const float* __restrict__ vin,
    const float* __restrict__ qprime, const float* __restrict__ qls,
    const float* __restrict__ kprime, const float* __restrict__ klsArr,
    const float* __restrict__ ksum, const float* __restrict__ kv,
    float* __restrict__ outp)
{
    __shared__ float QKb[32 * 132];
    __shared__ float DPb[32 * 132];
    __shared__ float QPb[32 * 132];
    int tid = threadIdx.x;
    int h = blockIdx.x >> 5;
    int t0 = (blockIdx.x & 31) * 32;
    int tl = tid >> 3, sub = tid & 7;
    int t = t0 + tl;
    int gid = t * 8 + h;

#pragma unroll
    for (int i = 0; i < 16; ++i) {
        int f = tid + 256 * i;
        int row = f >> 7, col = f & 127;
        QKb[row * 132 + col] = -INFINITY;
        DPb[row * 132 + col] = 0.f;
    }

    float qe[8], qp16[16];
    const float* qrow = q + ((size_t)gid << 6) + sub * 8;
#pragma unroll
    for (int i = 0; i < 8; ++i) qe[i] = qrow[i];
    const float* qpr = qprime + ((size_t)gid << 7) + sub * 16;
    const float* ksh = ksum + h * 128 + sub * 16;
    float qk1 = 0.f;
#pragma unroll
    for (int i = 0; i < 16; ++i) {
        qp16[i] = qpr[i];
        QPb[tl * 132 + sub * 16 + i] = qp16[i];
        qk1 += qp16[i] * ksh[i];
    }
#pragma unroll
    for (int mk = 1; mk < 8; mk <<= 1) qk1 += __shfl_xor(qk1, mk, 8);
    float pls = qls[gid] + klsArr[h];
    __syncthreads();

    // pass 1: QK and dots_prime over the union window
    for (int it = 0; it < 159; ++it) {
        int s = t0 - 64 + it;
        if (s < 0 || s >= 1024) continue;
        int sg = s * 8 + h;
        const float* krow = k + ((size_t)sg << 6) + sub * 8;
        float qdot = 0.f;
#pragma unroll
        for (int i = 0; i < 8; ++i) qdot += qe[i] * krow[i];
#pragma unroll
        for (int mk = 1; mk < 8; mk <<= 1) qdot += __shfl_xor(qdot, mk, 8);
        const float* kpr = kprime + ((size_t)sg << 7) + sub * 16;
        float dp = 0.f;
#pragma unroll
        for (int i = 0; i < 16; ++i) dp += qp16[i] * kpr[i];
#pragma unroll
        for (int mk = 1; mk < 8; mk <<= 1) dp += __shfl_xor(dp, mk, 8);
        int j = s - t + 64;
        if (j >= 0 && j < 128 && sub == 0) {
            QKb[tl * 132 + j] = TEMP * qdot;
            DPb[tl * 132 + j] = dp;
        }
    }
    __syncthreads();

    // pass 1.5: lse, dp_sum, log_norm, prime_scale
    float mx = -INFINITY, dsum = 0.f;
#pragma unroll
    for (int i = 0; i < 16; ++i) {
        mx = fmaxf(mx, QKb[tl * 132 + sub * 16 + i]);
        dsum += DPb[tl * 132 + sub * 16 + i];
    }
#pragma unroll
    for (int mk = 1; mk < 8; mk <<= 1) {
        mx = fmaxf(mx, __shfl_xor(mx, mk, 8));
        dsum += __shfl_xor(dsum, mk, 8);
    }
    float se = 0.f;
#pragma unroll
    for (int i = 0; i < 16; ++i) se += expf(QKb[tl * 132 + sub * 16 + i] - mx);
#pragma unroll
    for (int mk = 1; mk < 8; mk <<= 1) se += __shfl_xor(se, mk, 8);
    float lse = mx + logf(se);
    float lr = logf(fmaxf(qk1 - dsum, 1e-24f)) + pls;
    float mab = fmaxf(lse, lr);
    float log_norm = mab + log1pf(expf(fminf(lse, lr) - mab));
    float ps = expf(pls - log_norm);

    // qkv = q_prime @ kv, scaled by prime_scale
    float acc[8];
#pragma unroll
    for (int i = 0; i < 8; ++i) acc[i] = 0.f;
    const float* kvh = kv + h * 8192 + sub * 8;
    for (int m = 0; m < 128; ++m) {
        float qpm = QPb[tl * 132 + m];
#pragma unroll
        for (int i = 0; i < 8; ++i) acc[i] += qpm * kvh[m * 64 + i];
    }
#pragma unroll
    for (int i = 0; i < 8; ++i) acc[i] *= ps;

    // pass 2a: attn_local in place
#pragma unroll
    for (int i = 0; i < 16; ++i) {
        int j = sub * 16 + i;
        float vqk = QKb[tl * 132 + j];
        float at = expf(vqk - log_norm) - DPb[tl * 132 + j] * ps;
        QKb[tl * 132 + j] = at;
    }
    __syncthreads();

    // pass 2b: out_local accumulate
    for (int j = 0; j < 128; ++j) {
        float at = QKb[tl * 132 + j];
        int s = t - 64 + j;
        s = min(max(s, 0), 1023);
        const float* vrow = vin + ((size_t)(s * 8 + h) << 6) + sub * 8;
#pragma unroll
        for (int i = 0; i < 8; ++i) acc[i] += at * vrow[i];
    }

    float* dst = outp + ((size_t)gid << 6) + sub * 8;
#pragma unroll
    for (int i = 0; i < 8; ++i) dst[i] = acc[i];
}

extern "C" void kernel_launch(void* const* d_in, const int* in_sizes, int n_in,
                              void* d_out, int out_size, void* d_ws, size_t ws_size,
                              hipStream_t stream) {
    const float* q    = (const float*)d_in[0];
    const float* kk   = (const float*)d_in[1];
    const float* vv   = (const float*)d_in[2];
    const float* proj = (const float*)d_in[3];
    float* out = (float*)d_out;
    float* ws  = (float*)d_ws;

    float* qprime = ws;                    // 8192*128
    float* qls    = qprime + 1048576;      // 8192
    float* kdash  = qls    + 8192;         // 8192*64
    float* kdiag  = kdash  + 524288;       // 8192
    float* krmax  = kdiag  + 8192;         // 8192
    float* kls    = krmax  + 8192;         // 8 (pad 64)
    float* kprime = kls    + 64;           // 8192*128
    float* pksum  = kprime + 1048576;      // 8*16*128
    float* pkv    = pksum  + 16384;        // 8*16*128*64
    float* ksum   = pkv    + 1048576;      // 8*128
    float* kv     = ksum   + 1024;         // 8*128*64

    feat_kernel<true ><<<2048, 256, 0, stream>>>(q,  proj, qprime, qls, nullptr, nullptr);
    feat_kernel<false><<<2048, 256, 0, stream>>>(kk, proj, kdash, nullptr, kdiag, krmax);
    kls_kernel<<<8, 256, 0, stream>>>(krmax, kls);
    kprime_kv_kernel<<<128, 256, 0, stream>>>(kdash, kdiag, kls, vv, kprime, pksum, pkv);
    kvred_kernel<<<260, 256, 0, stream>>>(pkv, pksum, kv, ksum);
    main_kernel<<<256, 256, 0, stream>>>(q, kk, vv, qprime, qls, kprime, kls, ksum, kv, out);
}

// Round 2
// 71.792 us; speedup vs baseline: 2.0364x; 2.0364x over previous
//
#include <hip/hip_runtime.h>
#include <hip/hip_bf16.h>
#include <math.h>

#define DN     0.35355339059327373f   /* sqrt(1/8) */
#define RATIO  0.08838834764831845f   /* 1/sqrt(128) */
#define TEMP   0.125f

typedef short s16x8 __attribute__((ext_vector_type(8)));
typedef float f32x4 __attribute__((ext_vector_type(4)));

static __device__ __forceinline__ ushort f2bf(float f) {
    __hip_bfloat16 h = __float2bfloat16(f);
    return *reinterpret_cast<ushort*>(&h);
}
static __device__ __forceinline__ float bf2f(ushort u) {
    __hip_bfloat16 h = *reinterpret_cast<__hip_bfloat16*>(&u);
    return __bfloat162float(h);
}

// ---------------- feature kernel: blocks [0,2048) = q, [2048,4096) = k ----------
__global__ __launch_bounds__(256) void feat_kernel(const float* __restrict__ qin,
    const float* __restrict__ kin, const float* __restrict__ proj,
    ushort* __restrict__ qp_b, ushort* __restrict__ qb, float* __restrict__ qls,
    float* __restrict__ kdash, float* __restrict__ kdiag, float* __restrict__ krmax,
    ushort* __restrict__ kb)
{
    __shared__ float pT[64 * 64];     // proj transposed: pT[e][r]
    __shared__ float rowbuf[4][64];
    int tid = threadIdx.x;
    bool isq = blockIdx.x < 2048;
    const float* data = isq ? qin : kin;
    int bb = blockIdx.x & 2047;
#pragma unroll
    for (int i = 0; i < 16; ++i) {
        int f = tid * 16 + i;
        int r = f >> 6, e = f & 63;
        pT[e * 64 + r] = proj[f];
    }
    int wave = tid >> 6, lane = tid & 63;
    int gid = bb * 4 + wave;            // gid = t*8 + h
    const float* row = data + ((size_t)gid << 6);
    float x = row[lane];
    rowbuf[wave][lane] = x;
    __syncthreads();

    float qq = x * x;
#pragma unroll
    for (int m = 1; m < 64; m <<= 1) qq += __shfl_xor(qq, m, 64);
    float diag = 0.0625f * qq;

    float dash = 0.f;
#pragma unroll
    for (int e = 0; e < 64; ++e) dash += rowbuf[wave][e] * pT[e * 64 + lane];
    dash *= DN;

    float ad = fabsf(dash);
#pragma unroll
    for (int m = 1; m < 64; m <<= 1) ad = fmaxf(ad, __shfl_xor(ad, m, 64));

    if (isq) {
        qp_b[((size_t)gid << 7) + lane]      = f2bf(RATIO * __expf(dash - ad));
        qp_b[((size_t)gid << 7) + 64 + lane] = f2bf(RATIO * __expf(-dash - ad));
        qb[((size_t)gid << 6) + lane] = f2bf(x);
        if (lane == 0) qls[gid] = ad - diag;
    } else {
        kdash[((size_t)gid << 6) + lane] = dash;
        kb[((size_t)gid << 6) + lane] = f2bf(x);
        if (lane == 0) { kdiag[gid] = diag; krmax[gid] = ad - diag; }
    }
}

// ---------------- k_prime + partial ksum / kv (kls folded in) ----------------
__global__ __launch_bounds__(256) void kprime_kv_kernel(const float* __restrict__ kdash,
    const float* __restrict__ kdiag, const float* __restrict__ krmax,
    float* __restrict__ kls_g,
    const float* __restrict__ vin, ushort* __restrict__ kp_b,
    float* __restrict__ pksum, float* __restrict__ pkv)
{
    __shared__ float kp_lds[64][128];
    __shared__ float v_lds[64][64];
    __shared__ float wm[4];
    int tid = threadIdx.x;
    int chunk = blockIdx.x & 15, h = blockIdx.x >> 4;

    float lm = -1e30f;
#pragma unroll
    for (int i = 0; i < 4; ++i) {
        int s = tid + 256 * i;
        lm = fmaxf(lm, krmax[s * 8 + h]);
    }
#pragma unroll
    for (int m = 1; m < 64; m <<= 1) lm = fmaxf(lm, __shfl_xor(lm, m, 64));
    if ((tid & 63) == 0) wm[tid >> 6] = lm;
    __syncthreads();
    float ls = fmaxf(fmaxf(wm[0], wm[1]), fmaxf(wm[2], wm[3]));
    if (chunk == 0 && tid == 0) kls_g[h] = ls;

    int s0 = chunk * 64;
    int m = tid & 127, sg = tid >> 7;
    int r = m & 63;
    float sgn = (m < 64) ? 1.f : -1.f;
    for (int sl = sg; sl < 64; sl += 2) {
        int gid = (s0 + sl) * 8 + h;
        float dash = kdash[((size_t)gid << 6) + r];
        float val = RATIO * __expf(sgn * dash - kdiag[gid] - ls);
        kp_lds[sl][m] = val;
        kp_b[((size_t)gid << 7) + m] = f2bf(val);
    }
#pragma unroll
    for (int i = 0; i < 16; ++i) {
        int f = tid * 16 + i;
        int sl = f >> 6, e = f & 63;
        v_lds[sl][e] = vin[((size_t)((s0 + sl) * 8 + h) << 6) + e];
    }
    __syncthreads();
    if (tid < 128) {
        float s = 0.f;
        for (int sl = 0; sl < 64; ++sl) s += kp_lds[sl][tid];
        pksum[(h * 16 + chunk) * 128 + tid] = s;
    }
    int d0 = sg * 32;
    float acc[32];
#pragma unroll
    for (int i = 0; i < 32; ++i) acc[i] = 0.f;
    for (int sl = 0; sl < 64; ++sl) {
        float kpv = kp_lds[sl][m];
#pragma unroll
        for (int i = 0; i < 32; ++i) acc[i] += kpv * v_lds[sl][d0 + i];
    }
    float* dst = pkv + ((size_t)((h * 16 + chunk) * 128 + m) << 6) + d0;
#pragma unroll
    for (int i = 0; i < 32; ++i) dst[i] = acc[i];
}

// ---------------- reduce partial kv / ksum ----------------
__global__ __launch_bounds__(256) void kvred_kernel(const float* __restrict__ pkv,
    const float* __restrict__ pksum, float* __restrict__ kv, float* __restrict__ ksum)
{
    int idx = blockIdx.x * 256 + threadIdx.x;
    if (idx < 65536) {
        int h = idx >> 13, md = idx & 8191;
        float s = 0.f;
#pragma unroll
        for (int c = 0; c < 16; ++c) s += pkv[((size_t)(h * 16 + c) << 13) + md];
        kv[idx] = s;
    } else if (idx < 66560) {
        int j = idx - 65536;
        int h = j >> 7, mm = j & 127;
        float s = 0.f;
#pragma unroll
        for (int c = 0; c < 16; ++c) s += pksum[(h * 16 + c) * 128 + mm];
        ksum[j] = s;
    }
}

// ---------------- main: MFMA local window + long-range combine ----------------
__global__ __launch_bounds__(512) void main_kernel(const float* __restrict__ vin,
    const ushort* __restrict__ qp_b, const ushort* __restrict__ qb,
    const float* __restrict__ qls, const ushort* __restrict__ kb,
    const ushort* __restrict__ kp_b, const float* __restrict__ kls_g,
    const float* __restrict__ ksum, const float* __restrict__ kv,
    float* __restrict__ outp)
{
    __shared__ float QKb[32][168];
    __shared__ float DPb[32][168];
    __shared__ ushort ATb[32][168];
    __shared__ ushort VTb[64][168];
    __shared__ ushort KVTb[64][136];
    __shared__ float qk1s[32], plss[32], lns[32], pss[32];

    int tid = threadIdx.x;
    int h = blockIdx.x >> 5, t0 = (blockIdx.x & 31) << 5;
    int lane = tid & 63, w = tid >> 6;
    int tl = tid >> 4, sub = tid & 15;
    int l15 = lane & 15, lk = lane >> 4;

    // ---- phase 0: zero ATb, stage VTb/KVTb (transposed bf16), row scalars ----
    {
        uint* atz = (uint*)&ATb[0][0];
        for (int i = tid; i < 32 * 168 / 2; i += 512) atz[i] = 0;
    }
    for (int cs = w; cs < 160; cs += 8) {
        int s = min(max(t0 - 64 + cs, 0), 1023);
        VTb[lane][cs] = f2bf(vin[((size_t)(s * 8 + h) << 6) + lane]);
    }
    for (int m = w; m < 128; m += 8) {
        KVTb[lane][m] = f2bf(kv[(h << 13) + (m << 6) + lane]);
    }
    {
        int gid = (t0 + tl) * 8 + h;
        const ushort* qpp = qp_b + ((size_t)gid << 7) + sub * 8;
        const float* ksp = ksum + h * 128 + sub * 8;
        float s = 0.f;
#pragma unroll
        for (int i = 0; i < 8; ++i) s += bf2f(qpp[i]) * ksp[i];
#pragma unroll
        for (int m = 1; m < 16; m <<= 1) s += __shfl_xor(s, m, 16);
        if (sub == 0) qk1s[tl] = s;
        if (sub == 1) plss[tl] = qls[gid] + kls_g[h];
    }
    __syncthreads();

    // ---- phase 1: QK & DP GEMMs ----
    s16x8 aq[2][2], ap[2][4];
#pragma unroll
    for (int mt = 0; mt < 2; ++mt) {
        int tg = (t0 + mt * 16 + l15) * 8 + h;
#pragma unroll
        for (int kt = 0; kt < 2; ++kt)
            aq[mt][kt] = *(const s16x8*)(qb + ((size_t)tg << 6) + kt * 32 + lk * 8);
#pragma unroll
        for (int kt = 0; kt < 4; ++kt)
            ap[mt][kt] = *(const s16x8*)(qp_b + ((size_t)tg << 7) + kt * 32 + lk * 8);
    }
    for (int nt = w; nt < 10; nt += 8) {
        int srow = min(max(t0 - 64 + nt * 16 + l15, 0), 1023);
        int sgid = srow * 8 + h;
        s16x8 bk[2], bp[4];
#pragma unroll
        for (int kt = 0; kt < 2; ++kt)
            bk[kt] = *(const s16x8*)(kb + ((size_t)sgid << 6) + kt * 32 + lk * 8);
#pragma unroll
        for (int kt = 0; kt < 4; ++kt)
            bp[kt] = *(const s16x8*)(kp_b + ((size_t)sgid << 7) + kt * 32 + lk * 8);
        f32x4 aqk[2] = {{0,0,0,0},{0,0,0,0}}, adp[2] = {{0,0,0,0},{0,0,0,0}};
#pragma unroll
        for (int mt = 0; mt < 2; ++mt) {
#pragma unroll
            for (int kt = 0; kt < 2; ++kt)
                aqk[mt] = __builtin_amdgcn_mfma_f32_16x16x32_bf16(aq[mt][kt], bk[kt], aqk[mt], 0, 0, 0);
#pragma unroll
            for (int kt = 0; kt < 4; ++kt)
                adp[mt] = __builtin_amdgcn_mfma_f32_16x16x32_bf16(ap[mt][kt], bp[kt], adp[mt], 0, 0, 0);
        }
#pragma unroll
        for (int mt = 0; mt < 2; ++mt)
#pragma unroll
            for (int r = 0; r < 4; ++r) {
                int row = mt * 16 + lk * 4 + r, cs = nt * 16 + l15;
                QKb[row][cs] = TEMP * aqk[mt][r];
                DPb[row][cs] = adp[mt][r];
            }
    }
    __syncthreads();

    // ---- phase 1.5: row stats ----
    int clo = max(tl, 64 - t0);
    int chi = min(tl + 128, 1088 - t0);
    float mx = -1e30f, dsum = 0.f;
#pragma unroll
    for (int kk = 0; kk < 10; ++kk) {
        int cs = sub + 16 * kk;
        if (cs >= clo && cs < chi) {
            mx = fmaxf(mx, QKb[tl][cs]);
            dsum += DPb[tl][cs];
        }
    }
#pragma unroll
    for (int m = 1; m < 16; m <<= 1) {
        mx = fmaxf(mx, __shfl_xor(mx, m, 16));
        dsum += __shfl_xor(dsum, m, 16);
    }
    float se = 0.f;
#pragma unroll
    for (int kk = 0; kk < 10; ++kk) {
        int cs = sub + 16 * kk;
        if (cs >= clo && cs < chi) se += __expf(QKb[tl][cs] - mx);
    }
#pragma unroll
    for (int m = 1; m < 16; m <<= 1) se += __shfl_xor(se, m, 16);
    if (sub == 0) {
        float lse = mx + __logf(se);
        float lr = __logf(fmaxf(qk1s[tl] - dsum, 1e-24f)) + plss[tl];
        float mab = fmaxf(lse, lr);
        float ln = mab + log1pf(__expf(fminf(lse, lr) - mab));
        lns[tl] = ln;
        pss[tl] = __expf(plss[tl] - ln);
    }
    __syncthreads();

    // ---- phase 2a: attn_local -> bf16 s-aligned buffer ----
    {
        float ln = lns[tl], ps = pss[tl];
#pragma unroll
        for (int kk = 0; kk < 10; ++kk) {
            int cs = sub + 16 * kk;
            if (cs >= clo && cs < chi) {
                float att = __expf(QKb[tl][cs] - ln) - DPb[tl][cs] * ps;
                ATb[tl][cs] = f2bf(att);
            }
        }
    }
    __syncthreads();

    // ---- phase 2b: out = attn_sb @ V + ps * (q' @ kv) ----
    int Mt = w >> 2, Nt = w & 3;
    f32x4 acc1 = {0,0,0,0}, acc2 = {0,0,0,0};
#pragma unroll
    for (int kt = 0; kt < 5; ++kt) {
        s16x8 a = *(const s16x8*)&ATb[Mt * 16 + l15][kt * 32 + lk * 8];
        s16x8 b = *(const s16x8*)&VTb[Nt * 16 + l15][kt * 32 + lk * 8];
        acc1 = __builtin_amdgcn_mfma_f32_16x16x32_bf16(a, b, acc1, 0, 0, 0);
    }
#pragma unroll
    for (int kt = 0; kt < 4; ++kt) {
        s16x8 b = *(const s16x8*)&KVTb[Nt * 16 + l15][kt * 32 + lk * 8];
        acc2 = __builtin_amdgcn_mfma_f32_16x16x32_bf16(ap[Mt][kt], b, acc2, 0, 0, 0);
    }
#pragma unroll
    for (int r = 0; r < 4; ++r) {
        int row = Mt * 16 + lk * 4 + r;
        int t = t0 + row;
        float val = acc1[r] + pss[row] * acc2[r];
        outp[((size_t)(t * 8 + h) << 6) + Nt * 16 + l15] = val;
    }
}

extern "C" void kernel_launch(void* const* d_in, const int* in_sizes, int n_in,
                              void* d_out, int out_size, void* d_ws, size_t ws_size,
                              hipStream_t stream) {
    const float* q    = (const float*)d_in[0];
    const float* kk   = (const float*)d_in[1];
    const float* vv   = (const float*)d_in[2];
    const float* proj = (const float*)d_in[3];
    float* out = (float*)d_out;
    float* ws  = (float*)d_ws;

    ushort* qp_b  = (ushort*)ws;               // 8192*128 bf16 (524288 f32 slots)
    ushort* qb    = (ushort*)(ws + 524288);    // 8192*64  bf16 (262144)
    float*  qls   = ws + 786432;               // 8192
    float*  kdash = ws + 794624;               // 524288
    float*  kdiag = ws + 1318912;              // 8192
    float*  krmax = ws + 1327104;              // 8192
    float*  kls_g = ws + 1335296;              // 64
    ushort* kp_b  = (ushort*)(ws + 1335360);   // 8192*128 bf16 (524288)
    float*  pksum = ws + 1859648;              // 16384
    float*  pkv   = ws + 1876032;              // 1048576
    float*  ksum  = ws + 2924608;              // 1024
    float*  kv    = ws + 2925632;              // 65536
    ushort* kb    = (ushort*)(ws + 2991168);   // 8192*64 bf16 (262144) -> ends 3253312

    feat_kernel<<<4096, 256, 0, stream>>>(q, kk, proj, qp_b, qb, qls,
                                          kdash, kdiag, krmax, kb);
    kprime_kv_kernel<<<128, 256, 0, stream>>>(kdash, kdiag, krmax, kls_g, vv,
                                              kp_b, pksum, pkv);
    kvred_kernel<<<260, 256, 0, stream>>>(pkv, pksum, kv, ksum);
    main_kernel<<<256, 512, 0, stream>>>(vv, qp_b, qb, qls, kb, kp_b, kls_g,
                                         ksum, kv, out);
}